// Round 7
// baseline (447.899 us; speedup 1.0000x reference)
//
#include <hip/hip_runtime.h>

#define HIDDEN 2048
#define NQ     1024
#define NCTX   2048
#define NTOT   3072
#define NHEADS 32
#define KVH    8
#define HD     128

typedef __attribute__((ext_vector_type(8))) __bf16 bf16x8;
typedef __attribute__((ext_vector_type(4))) __bf16 bf16x4;
typedef __attribute__((ext_vector_type(4))) float  f32x4;

#define MFMA16(a, b, c) __builtin_amdgcn_mfma_f32_16x16x32_bf16(a, b, c, 0, 0, 0)

// Fixed softmax shift (Cauchy-Schwarz: |q|=1 after folded 1/sqrt(d), |k|=sqrt(128),
// RoPE norm-preserving => s <= 11.4 incl. bf16 rounding).
#define MSTATIC 12.0f

__device__ __forceinline__ void load_lds16(const void* g, void* l) {
    __builtin_amdgcn_global_load_lds(
        (const __attribute__((address_space(1))) unsigned int*)g,
        (__attribute__((address_space(3))) unsigned int*)l, 16, 0, 0);
}

// ---------------------------------------------------------------------------
// z-fused fp32 -> bf16 convert (activations only; weights never converted)
// ---------------------------------------------------------------------------
__global__ __launch_bounds__(256) void conv2_f32_bf16(const float* __restrict__ s0,
                                                      __bf16* __restrict__ d0, int n0,
                                                      const float* __restrict__ s1,
                                                      __bf16* __restrict__ d1, int n1) {
    const float* s = blockIdx.y ? s1 : s0;
    __bf16*      d = blockIdx.y ? d1 : d0;
    int          n = blockIdx.y ? n1 : n0;
    int i = blockIdx.x * 256 + threadIdx.x;
    int stride = gridDim.x * 256;
    for (; i < n; i += stride) {
        float4 v = ((const float4*)s)[i];
        bf16x4 o;
        o[0] = (__bf16)v.x; o[1] = (__bf16)v.y;
        o[2] = (__bf16)v.z; o[3] = (__bf16)v.w;
        ((bf16x4*)d)[i] = o;
    }
}

// ---------------------------------------------------------------------------
// 128x128 MFMA GEMM tile body; A bf16 async-staged, B fp32 async-staged RAW
// (global_load_lds moves bytes; fp32->bf16 happens at fragment-read time).
// LDS: As 16 KB + Bsf 32 KB = 48 KB -> 3 blocks/CU.
// ---------------------------------------------------------------------------
template <typename OutT>
__device__ __forceinline__ void gemm128_f32b(const __bf16* __restrict__ Ablk,
                                             const float* __restrict__ Bblk,
                                             OutT* __restrict__ Cblk,
                                             int K, int lda, int ldb, int ldc) {
    __shared__ __bf16 As[128][64];     // 16 KB
    __shared__ float  Bsf[128][64];    // 32 KB

    const int tid  = threadIdx.x;
    const int lane = tid & 63;
    const int w    = tid >> 6;
    const int n16  = lane & 15;
    const int quad = lane >> 4;
    const int wm = (w & 1) * 64;
    const int wn = (w >> 1) * 64;

    f32x4 acc[4][4];
    const f32x4 fzero = {0.f, 0.f, 0.f, 0.f};
#pragma unroll
    for (int i = 0; i < 4; i++)
#pragma unroll
        for (int j = 0; j < 4; j++) acc[i][j] = fzero;

    // A staging: 8 lanes/row (16B each), 8 rows/issue, 4 issues -> 32 rows/wave
    const int arow = w * 32 + (lane >> 3);
    const int acol = (lane & 7) * 8;
    // B staging: 16 lanes/row (16B = 4 floats each), 4 rows/issue, 8 issues
    const int brow = w * 32 + (lane >> 4);
    const int bcol = (lane & 15) * 4;

    for (int k0 = 0; k0 < K; k0 += 64) {
#pragma unroll
        for (int i = 0; i < 4; i++)
            load_lds16(Ablk + (long)(arow + i * 8) * lda + k0 + acol,
                       &As[arow + i * 8][acol]);
#pragma unroll
        for (int i = 0; i < 8; i++)
            load_lds16(Bblk + (long)(brow + i * 4) * ldb + k0 + bcol,
                       &Bsf[brow + i * 4][bcol]);
        __syncthreads();
#pragma unroll
        for (int ks = 0; ks < 2; ks++) {
            bf16x8 af[4], bfr[4];
#pragma unroll
            for (int i = 0; i < 4; i++)
                af[i] = *(const bf16x8*)&As[wm + i * 16 + n16][ks * 32 + quad * 8];
#pragma unroll
            for (int j = 0; j < 4; j++) {
                f32x4 b0 = *(const f32x4*)&Bsf[wn + j * 16 + n16][ks * 32 + quad * 8];
                f32x4 b1 = *(const f32x4*)&Bsf[wn + j * 16 + n16][ks * 32 + quad * 8 + 4];
                bf16x8 bb;
                bb[0] = (__bf16)b0[0]; bb[1] = (__bf16)b0[1];
                bb[2] = (__bf16)b0[2]; bb[3] = (__bf16)b0[3];
                bb[4] = (__bf16)b1[0]; bb[5] = (__bf16)b1[1];
                bb[6] = (__bf16)b1[2]; bb[7] = (__bf16)b1[3];
                bfr[j] = bb;
            }
#pragma unroll
            for (int i = 0; i < 4; i++)
#pragma unroll
                for (int j = 0; j < 4; j++)
                    acc[i][j] = MFMA16(af[i], bfr[j], acc[i][j]);
        }
        __syncthreads();
    }

#pragma unroll
    for (int i = 0; i < 4; i++)
#pragma unroll
        for (int j = 0; j < 4; j++)
#pragma unroll
            for (int r = 0; r < 4; r++)
                Cblk[(long)(wm + i * 16 + quad * 4 + r) * ldc + wn + j * 16 + n16] =
                    (OutT)acc[i][j][r];
}

// ---------------------------------------------------------------------------
// Fused k + v + q projections in ONE launch (640 blocks, all co-resident).
// blocks 0..191: k, 192..383: v, 384..639: q.
// ---------------------------------------------------------------------------
__global__ __launch_bounds__(256) void gemm_kvq(const __bf16* __restrict__ tgtb,
                                                const __bf16* __restrict__ hidb,
                                                const float* __restrict__ wk,
                                                const float* __restrict__ wv,
                                                const float* __restrict__ wq,
                                                __bf16* __restrict__ kbf,
                                                __bf16* __restrict__ vbf,
                                                __bf16* __restrict__ qbf) {
    const int b = blockIdx.x;
    const __bf16* Ap; const float* Bp; __bf16* Cp; int ldc;
    if (b < 384) {
        const int z = b / 192, bb = b - z * 192;
        const int n0 = (bb & 7) * 128, m0 = (bb >> 3) * 128;
        Ap = (m0 < 2048) ? tgtb + (long)m0 * 2048 : hidb + (long)(m0 - 2048) * 2048;
        Bp = (z ? wv : wk) + (long)n0 * 2048;
        Cp = (z ? vbf : kbf) + (long)m0 * 1024 + n0;
        ldc = 1024;
    } else {
        const int bb = b - 384;
        const int n0 = (bb & 31) * 128, m0 = (bb >> 5) * 128;
        Ap = hidb + (long)m0 * 2048;
        Bp = wq + (long)n0 * 2048;
        Cp = qbf + (long)m0 * 4096 + n0;
        ldc = 4096;
    }
    gemm128_f32b<__bf16>(Ap, Bp, Cp, 2048, 2048, 2048, ldc);
}

// ---------------------------------------------------------------------------
// Output projection, split-K=4 (512 blocks), fp32 partials.
// ---------------------------------------------------------------------------
__global__ __launch_bounds__(256) void gemm_wo_splitk(const __bf16* __restrict__ A,
                                                      const float* __restrict__ B,
                                                      float* __restrict__ po) {
    const int m0 = blockIdx.y * 128;
    const int n0 = blockIdx.x * 128;
    const int koff = blockIdx.z * 1024;
    float* C = po + (long)blockIdx.z * 1024 * 2048;
    gemm128_f32b<float>(A + (long)m0 * 4096 + koff, B + (long)n0 * 4096 + koff,
                        C + (long)m0 * 2048 + n0, 1024, 4096, 4096, 2048);
}

__global__ __launch_bounds__(256) void add4(const float* __restrict__ po,
                                            float* __restrict__ out, int n4) {
    int i = blockIdx.x * 256 + threadIdx.x;
    int stride = gridDim.x * 256;
    const long seg = (long)1024 * 2048 / 4;
    for (; i < n4; i += stride) {
        float4 a = ((const float4*)po)[i];
        float4 b = ((const float4*)po)[i + seg];
        float4 c = ((const float4*)po)[i + 2 * seg];
        float4 d = ((const float4*)po)[i + 3 * seg];
        float4 o;
        o.x = (a.x + b.x) + (c.x + d.x);
        o.y = (a.y + b.y) + (c.y + d.y);
        o.z = (a.z + b.z) + (c.z + d.z);
        o.w = (a.w + b.w) + (c.w + d.w);
        ((float4*)out)[i] = o;
    }
}

// ---------------------------------------------------------------------------
// Fused RMSNorm+RoPE for q (z=0) and k (z=1), in place.
// ---------------------------------------------------------------------------
__global__ __launch_bounds__(256) void rmsnorm_rope2(__bf16* __restrict__ xq,
                                                     const float* __restrict__ wq,
                                                     __bf16* __restrict__ xk,
                                                     const float* __restrict__ wk,
                                                     const float* __restrict__ cosb,
                                                     const float* __restrict__ sinb) {
    const int z = blockIdx.y;
    __bf16*      x = z ? xk : xq;
    const float* w = z ? wk : wq;
    const int nheads     = z ? 8 : 32;
    const int row_stride = z ? 1024 : 4096;
    const int pos_offset = z ? 0 : 2048;
    const float outscale = z ? 1.0f : 0.08838834764831845f;
    const int nitems     = z ? 3072 * 8 : 1024 * 32;

    int item = blockIdx.x * 4 + (threadIdx.x >> 6);
    int lane = threadIdx.x & 63;
    if (item >= nitems) return;
    int row = item / nheads;
    int head = item - row * nheads;
    __bf16* p = x + (long)row * row_stride + head * HD;

    float x1 = (float)p[lane], x2 = (float)p[lane + 64];
    float ss = x1 * x1 + x2 * x2;
#pragma unroll
    for (int o = 32; o >= 1; o >>= 1) ss += __shfl_xor(ss, o);
    float r = rsqrtf(ss * (1.0f / 128.0f) + 1e-6f) * outscale;

    int pos = pos_offset + row;
    float c1 = cosb[pos * HD + lane], c2 = cosb[pos * HD + lane + 64];
    float s1 = sinb[pos * HD + lane], s2 = sinb[pos * HD + lane + 64];
    float y1 = x1 * r * w[lane];
    float y2 = x2 * r * w[lane + 64];
    p[lane]      = (__bf16)(y1 * c1 - y2 * s1);
    p[lane + 64] = (__bf16)(y2 * c2 + y1 * s2);
}

// ---------------------------------------------------------------------------
// V transpose: vbf[t][g*128+d] -> vt[g][d][t]
// ---------------------------------------------------------------------------
__global__ __launch_bounds__(256) void transpose_v(const __bf16* __restrict__ v,
                                                   __bf16* __restrict__ vt) {
    __shared__ __bf16 T[64][68];
    const int tid = threadIdx.x;
    const int t0 = blockIdx.x * 64;
    const int d0 = blockIdx.y * 64;
    const int g  = blockIdx.z;
    const __bf16* src = v + (long)t0 * 1024 + g * 128 + d0;
#pragma unroll
    for (int i = 0; i < 4; i++) {
        int idx = tid + i * 256;
        int r = idx >> 4, c4 = (idx & 15) * 4;
        *(bf16x4*)&T[r][c4] = *(const bf16x4*)(src + (long)r * 1024 + c4);
    }
    __syncthreads();
    __bf16* dst = vt + (long)g * 128 * 3072 + (long)d0 * 3072 + t0;
#pragma unroll
    for (int i = 0; i < 4; i++) {
        int idx = tid + i * 256;
        int r = idx >> 4, c4 = (idx & 15) * 4;
        bf16x4 o;
        o[0] = T[c4 + 0][r]; o[1] = T[c4 + 1][r];
        o[2] = T[c4 + 2][r]; o[3] = T[c4 + 3][r];
        *(bf16x4*)(dst + (long)r * 3072 + c4) = o;
    }
}

// ---------------------------------------------------------------------------
// Split-K flash attention, 128 q-rows per block (4 waves x 2 m-tiles of 16).
// Staged K/V fragments reused across both m-tiles. Fixed softmax shift;
// additive split-K merge. Ps aliases Ks (stride 68).
// ---------------------------------------------------------------------------
__global__ __launch_bounds__(256) void flash_attn_splitk(const __bf16* __restrict__ qb,
                                                         const __bf16* __restrict__ kb,
                                                         const __bf16* __restrict__ vtg,
                                                         __bf16* __restrict__ Opart0,
                                                         __bf16* __restrict__ Opart1,
                                                         float* __restrict__ lsum) {
    __shared__ __bf16 KsU[64 * 136];   // Ks[t][d] stride 136; Ps aliased (4*32*68 = 8704)
    __shared__ __bf16 Vs[128][72];     // [d][t]
#define KS(r, c) KsU[(r) * 136 + (c)]
#define PS(w_, m_, t_) KsU[(w_) * 2176 + (m_) * 68 + (t_)]

    const int tid  = threadIdx.x;
    const int lane = tid & 63;
    const int w    = tid >> 6;
    const int n    = lane & 15;
    const int quad = lane >> 4;

    const int bid = blockIdx.x;        // 0..255
    const int s   = blockIdx.y;
    const int g  = bid & 7;
    const int jj = bid >> 3;           // 0..31
    const int h  = g * 4 + (jj & 3);
    const int qt = jj >> 2;            // 0..7, 128-row q tiles

    const int qr0 = qt * 128 + w * 16; // m-tile 0 base; m-tile 1 = +64

    bf16x8 qf[2][4];
#pragma unroll
    for (int mt = 0; mt < 2; mt++) {
        const __bf16* qp = qb + (long)(qr0 + mt * 64 + n) * 4096 + h * 128 + quad * 8;
        qf[mt][0] = *(const bf16x8*)(qp);
        qf[mt][1] = *(const bf16x8*)(qp + 32);
        qf[mt][2] = *(const bf16x8*)(qp + 64);
        qf[mt][3] = *(const bf16x8*)(qp + 96);
    }

    f32x4 O[2][8];
    const f32x4 fzero = {0.f, 0.f, 0.f, 0.f};
#pragma unroll
    for (int mt = 0; mt < 2; mt++)
#pragma unroll
        for (int dt = 0; dt < 8; dt++) O[mt][dt] = fzero;
    float l_loc[2][4] = {{0.f, 0.f, 0.f, 0.f}, {0.f, 0.f, 0.f, 0.f}};

    const int ntot = 34 + 2 * qt;      // even
    const int half = ntot >> 1;
    const int tbeg = s ? half : 0;
    const int tend = s ? ntot : half;

    const int krr = tid >> 4, kc8 = (tid & 15) * 8;
    const int vrr = tid >> 3, vc8 = (tid & 7) * 8;
    const __bf16* kp = kb + g * 128 + (long)(tbeg * 64 + krr) * 1024 + kc8;
    const __bf16* vp = vtg + (long)g * 128 * 3072 + (long)vrr * 3072 + tbeg * 64 + vc8;

    for (int tt = tbeg; tt < tend; tt++) {
#pragma unroll
        for (int i = 0; i < 4; i++)
            *(bf16x8*)&KS(krr + i * 16, kc8) = *(const bf16x8*)(kp + (long)i * 16 * 1024);
#pragma unroll
        for (int i = 0; i < 4; i++)
            *(bf16x8*)&Vs[vrr + i * 32][vc8] = *(const bf16x8*)(vp + (long)i * 32 * 3072);
        kp += 64 * 1024;
        vp += 64;
        __syncthreads();

        // S = Q K^T, both m-tiles share each staged K fragment
        f32x4 S[2][4];
#pragma unroll
        for (int nt = 0; nt < 4; nt++) {
            f32x4 a0 = fzero, a1 = fzero;
#pragma unroll
            for (int ks = 0; ks < 4; ks++) {
                bf16x8 bfr = *(const bf16x8*)&KS(nt * 16 + n, ks * 32 + quad * 8);
                a0 = MFMA16(qf[0][ks], bfr, a0);
                a1 = MFMA16(qf[1][ks], bfr, a1);
            }
            S[0][nt] = a0;
            S[1][nt] = a1;
        }

        if (tt >= ntot - 2) {   // diagonal band spans the last two tiles
            const int t0 = tt * 64;
#pragma unroll
            for (int mt = 0; mt < 2; mt++)
#pragma unroll
                for (int nt = 0; nt < 4; nt++)
#pragma unroll
                    for (int r = 0; r < 4; r++) {
                        int t   = t0 + nt * 16 + n;
                        int lim = 2048 + qr0 + mt * 64 + quad * 4 + r;
                        if (t > lim) S[mt][nt][r] = -1e30f;
                    }
        }

        __syncthreads();   // all Ks reads done; Ps may overwrite

#pragma unroll
        for (int mt = 0; mt < 2; mt++)
#pragma unroll
            for (int nt = 0; nt < 4; nt++)
#pragma unroll
                for (int r = 0; r < 4; r++) {
                    float p = __expf(S[mt][nt][r] - MSTATIC);
                    S[mt][nt][r] = p;
                    l_loc[mt][r] += p;
                }

#pragma unroll
        for (int mt = 0; mt < 2; mt++)
#pragma unroll
            for (int nt = 0; nt < 4; nt++)
#pragma unroll
                for (int r = 0; r < 4; r++)
                    PS(w, mt * 16 + quad * 4 + r, nt * 16 + n) = (__bf16)S[mt][nt][r];

        bf16x8 pa[2][2];
#pragma unroll
        for (int mt = 0; mt < 2; mt++)
#pragma unroll
            for (int kg = 0; kg < 2; kg++)
                pa[mt][kg] = *(const bf16x8*)&PS(w, mt * 16 + n, kg * 32 + quad * 8);

#pragma unroll
        for (int dt = 0; dt < 8; dt++) {
            bf16x8 vf0 = *(const bf16x8*)&Vs[dt * 16 + n][quad * 8];
            bf16x8 vf1 = *(const bf16x8*)&Vs[dt * 16 + n][32 + quad * 8];
#pragma unroll
            for (int mt = 0; mt < 2; mt++) {
                f32x4 acc = O[mt][dt];
                acc = MFMA16(pa[mt][0], vf0, acc);
                acc = MFMA16(pa[mt][1], vf1, acc);
                O[mt][dt] = acc;
            }
        }
        __syncthreads();
    }

    // row-sum reduction across the 16 n-lanes, once per block
#pragma unroll
    for (int mt = 0; mt < 2; mt++)
#pragma unroll
        for (int r = 0; r < 4; r++) {
            float sm = l_loc[mt][r];
            sm += __shfl_xor(sm, 1);
            sm += __shfl_xor(sm, 2);
            sm += __shfl_xor(sm, 4);
            sm += __shfl_xor(sm, 8);
            l_loc[mt][r] = sm;
        }

    __bf16* Op = s ? Opart1 : Opart0;
    const long tb = (long)(h * 8 + qt) * 128 * 128;
#pragma unroll
    for (int mt = 0; mt < 2; mt++)
#pragma unroll
        for (int dt = 0; dt < 8; dt++)
#pragma unroll
            for (int r = 0; r < 4; r++)
                Op[tb + (long)(mt * 64 + w * 16 + quad * 4 + r) * 128 + dt * 16 + n] =
                    (__bf16)O[mt][dt][r];
    if (n == 0) {
        const int lb = (s * 256 + h * 8 + qt) * 128 + w * 16 + quad * 4;
#pragma unroll
        for (int mt = 0; mt < 2; mt++)
#pragma unroll
            for (int r = 0; r < 4; r++)
                lsum[lb + mt * 64 + r] = l_loc[mt][r];
    }
#undef KS
#undef PS
}

// ---------------------------------------------------------------------------
// Additive merge of split-K partials -> normalized bf16 O over qbf.
// ---------------------------------------------------------------------------
__global__ __launch_bounds__(256) void flash_merge(const __bf16* __restrict__ O0,
                                                   const __bf16* __restrict__ O1,
                                                   const float* __restrict__ lsum,
                                                   __bf16* __restrict__ ob) {
    const int bx = blockIdx.x;         // 512: (h, qt, half64)
    const int h   = bx >> 4;
    const int r6  = bx & 15;
    const int qt  = r6 >> 1;
    const int sub = r6 & 1;
    const int row  = threadIdx.x >> 2;
    const int cseg = (threadIdx.x & 3) * 32;
    const int mrow = sub * 64 + row;

    const int tilei = h * 8 + qt;
    float inv = 1.0f / (lsum[tilei * 128 + mrow] + lsum[(256 + tilei) * 128 + mrow]);

    const long src = (long)tilei * 128 * 128 + (long)mrow * 128 + cseg;
    __bf16* dst = ob + (long)(qt * 128 + mrow) * 4096 + h * 128 + cseg;
#pragma unroll
    for (int j = 0; j < 4; j++) {
        bf16x8 x0 = *(const bf16x8*)(O0 + src + j * 8);
        bf16x8 x1 = *(const bf16x8*)(O1 + src + j * 8);
        bf16x8 o;
#pragma unroll
        for (int k = 0; k < 8; k++)
            o[k] = (__bf16)(((float)x0[k] + (float)x1[k]) * inv);
        *(bf16x8*)(dst + j * 8) = o;
    }
}

// ---------------------------------------------------------------------------
extern "C" void kernel_launch(void* const* d_in, const int* in_sizes, int n_in,
                              void* d_out, int out_size, void* d_ws, size_t ws_size,
                              hipStream_t stream) {
    const float* hidden = (const float*)d_in[0];
    const float* target = (const float*)d_in[1];
    const float* cosb   = (const float*)d_in[2];
    const float* sinb   = (const float*)d_in[3];
    const float* wq = (const float*)d_in[5];
    const float* wk = (const float*)d_in[6];
    const float* wv = (const float*)d_in[7];
    const float* wo = (const float*)d_in[8];
    const float* qw = (const float*)d_in[9];
    const float* kw = (const float*)d_in[10];
    float* out = (float*)d_out;

    // 40 MB workspace, phased overlays (launch order guarantees safety):
    char* ws = (char*)d_ws;
    const long MB = 1 << 20;
    __bf16* qbf  = (__bf16*)(ws);             // @0..8    q / attn out (live throughout)
    __bf16* kbf  = (__bf16*)(ws + 8 * MB);    // @8..14   k (dead after flash)
    __bf16* vbf  = (__bf16*)(ws + 14 * MB);   // @14..20  v (dead after transpose)
    __bf16* hidb = (__bf16*)(ws + 20 * MB);   // @20..24  (dead after gemm_kvq)
    __bf16* tgtb = (__bf16*)(ws + 24 * MB);   // @24..32  (dead after gemm_kvq)
    __bf16* vtg  = (__bf16*)(ws + 24 * MB);   // @24..30  (post-kvq)
    __bf16* Op1  = (__bf16*)(ws + 14 * MB);   // @14..22  (post-transpose)
    float*  lbuf = (float*)(ws + 22 * MB);    // @22..22.25
    __bf16* Op0  = (__bf16*)(ws + 30 * MB);   // @30..38
    float*  po   = (float*)(ws + 8 * MB);     // @8..40   wo partials (post-merge)

    dim3 blk(256);

    // activations -> bf16
    conv2_f32_bf16<<<dim3(1024, 2), blk, 0, stream>>>(
        target, tgtb, (2048 * 2048) / 4, hidden, hidb, (1024 * 2048) / 4);

    // all three projections, one launch (weights fp32, async-staged raw)
    gemm_kvq<<<640, blk, 0, stream>>>(tgtb, hidb, wk, wv, wq, kbf, vbf, qbf);

    // fused RMSNorm + RoPE (q and k)
    rmsnorm_rope2<<<dim3(8192, 2), blk, 0, stream>>>(qbf, qw, kbf, kw, cosb, sinb);

    // V transpose -> [g][d][t]
    transpose_v<<<dim3(48, 2, 8), blk, 0, stream>>>(vbf, vtg);

    // split-K flash attention (512 blocks, 128 q-rows each) + additive merge
    flash_attn_splitk<<<dim3(256, 2), blk, 0, stream>>>(qbf, kbf, vtg, Op0, Op1, lbuf);
    flash_merge<<<512, blk, 0, stream>>>(Op0, Op1, lbuf, qbf);

    // output projection: split-K=4 (512 blocks) + reduce
    gemm_wo_splitk<<<dim3(16, 8, 4), blk, 0, stream>>>(qbf, wo, po);
    add4<<<1024, blk, 0, stream>>>(po, out, (1024 * 2048) / 4);
}

// Round 8
// 392.894 us; speedup vs baseline: 1.1400x; 1.1400x over previous
//
#include <hip/hip_runtime.h>

#define HIDDEN 2048
#define NQ     1024
#define NCTX   2048
#define NTOT   3072
#define NHEADS 32
#define KVH    8
#define HD     128

typedef __attribute__((ext_vector_type(8))) __bf16 bf16x8;
typedef __attribute__((ext_vector_type(4))) __bf16 bf16x4;
typedef __attribute__((ext_vector_type(4))) float  f32x4;

#define MFMA16(a, b, c) __builtin_amdgcn_mfma_f32_16x16x32_bf16(a, b, c, 0, 0, 0)

// Fixed softmax shift (Cauchy-Schwarz: |q|=1 after folded 1/sqrt(d), |k|=sqrt(128),
// RoPE norm-preserving => s <= 11.4 incl. bf16 rounding).
#define MSTATIC 12.0f

__device__ __forceinline__ void load_lds16(const void* g, void* l) {
    __builtin_amdgcn_global_load_lds(
        (const __attribute__((address_space(1))) unsigned int*)g,
        (__attribute__((address_space(3))) unsigned int*)l, 16, 0, 0);
}

// ---------------------------------------------------------------------------
// z-fused fp32 -> bf16 convert (activations only; weights convert in-GEMM)
// ---------------------------------------------------------------------------
__global__ __launch_bounds__(256) void conv2_f32_bf16(const float* __restrict__ s0,
                                                      __bf16* __restrict__ d0, int n0,
                                                      const float* __restrict__ s1,
                                                      __bf16* __restrict__ d1, int n1) {
    const float* s = blockIdx.y ? s1 : s0;
    __bf16*      d = blockIdx.y ? d1 : d0;
    int          n = blockIdx.y ? n1 : n0;
    int i = blockIdx.x * 256 + threadIdx.x;
    int stride = gridDim.x * 256;
    for (; i < n; i += stride) {
        float4 v = ((const float4*)s)[i];
        bf16x4 o;
        o[0] = (__bf16)v.x; o[1] = (__bf16)v.y;
        o[2] = (__bf16)v.z; o[3] = (__bf16)v.w;
        ((bf16x4*)d)[i] = o;
    }
}

// ---------------------------------------------------------------------------
// 128x128 MFMA GEMM tile body; A bf16 (async global->LDS), B fp32
// (register-staged + converted to bf16 in LDS). R6 version — the raw-fp32
// global_load_lds variant (R7) regressed via LDS bank conflicts.
// ---------------------------------------------------------------------------
template <typename OutT>
__device__ __forceinline__ void gemm128_f32b(const __bf16* __restrict__ Ablk,
                                             const float* __restrict__ Bblk,
                                             OutT* __restrict__ Cblk,
                                             int K, int lda, int ldb, int ldc) {
    __shared__ __bf16 As[128][64];
    __shared__ __bf16 Bs[128][64];

    const int tid  = threadIdx.x;
    const int lane = tid & 63;
    const int w    = tid >> 6;
    const int n16  = lane & 15;
    const int quad = lane >> 4;
    const int wm = (w & 1) * 64;
    const int wn = (w >> 1) * 64;

    f32x4 acc[4][4];
    const f32x4 fzero = {0.f, 0.f, 0.f, 0.f};
#pragma unroll
    for (int i = 0; i < 4; i++)
#pragma unroll
        for (int j = 0; j < 4; j++) acc[i][j] = fzero;

    const int srow = w * 32 + (lane >> 3);
    const int scol = (lane & 7) * 8;

    for (int k0 = 0; k0 < K; k0 += 64) {
        // A: async bf16 staging
#pragma unroll
        for (int i = 0; i < 4; i++) {
            int r = srow + i * 8;
            load_lds16(Ablk + (long)r * lda + k0 + scol, &As[r][scol]);
        }
        // B: fp32 load -> cvt -> LDS bf16
#pragma unroll
        for (int i = 0; i < 4; i++) {
            int id = tid + i * 256;
            int br = id >> 3, c8 = (id & 7) * 8;
            float4 f0 = *(const float4*)(Bblk + (long)br * ldb + k0 + c8);
            float4 f1 = *(const float4*)(Bblk + (long)br * ldb + k0 + c8 + 4);
            bf16x8 bb;
            bb[0] = (__bf16)f0.x; bb[1] = (__bf16)f0.y;
            bb[2] = (__bf16)f0.z; bb[3] = (__bf16)f0.w;
            bb[4] = (__bf16)f1.x; bb[5] = (__bf16)f1.y;
            bb[6] = (__bf16)f1.z; bb[7] = (__bf16)f1.w;
            *(bf16x8*)&Bs[br][c8] = bb;
        }
        __syncthreads();
#pragma unroll
        for (int ks = 0; ks < 2; ks++) {
            bf16x8 af[4], bfr[4];
#pragma unroll
            for (int i = 0; i < 4; i++)
                af[i] = *(const bf16x8*)&As[wm + i * 16 + n16][ks * 32 + quad * 8];
#pragma unroll
            for (int j = 0; j < 4; j++)
                bfr[j] = *(const bf16x8*)&Bs[wn + j * 16 + n16][ks * 32 + quad * 8];
#pragma unroll
            for (int i = 0; i < 4; i++)
#pragma unroll
                for (int j = 0; j < 4; j++)
                    acc[i][j] = MFMA16(af[i], bfr[j], acc[i][j]);
        }
        __syncthreads();
    }

#pragma unroll
    for (int i = 0; i < 4; i++)
#pragma unroll
        for (int j = 0; j < 4; j++)
#pragma unroll
            for (int r = 0; r < 4; r++)
                Cblk[(long)(wm + i * 16 + quad * 4 + r) * ldc + wn + j * 16 + n16] =
                    (OutT)acc[i][j][r];
}

// ---------------------------------------------------------------------------
// Fused k + v + q projections in ONE launch (640 blocks).
// blocks 0..191: k, 192..383: v, 384..639: q.
// ---------------------------------------------------------------------------
__global__ __launch_bounds__(256) void gemm_kvq(const __bf16* __restrict__ tgtb,
                                                const __bf16* __restrict__ hidb,
                                                const float* __restrict__ wk,
                                                const float* __restrict__ wv,
                                                const float* __restrict__ wq,
                                                __bf16* __restrict__ kbf,
                                                __bf16* __restrict__ vbf,
                                                __bf16* __restrict__ qbf) {
    const int b = blockIdx.x;
    const __bf16* Ap; const float* Bp; __bf16* Cp; int ldc;
    if (b < 384) {
        const int z = b / 192, bb = b - z * 192;
        const int n0 = (bb & 7) * 128, m0 = (bb >> 3) * 128;
        Ap = (m0 < 2048) ? tgtb + (long)m0 * 2048 : hidb + (long)(m0 - 2048) * 2048;
        Bp = (z ? wv : wk) + (long)n0 * 2048;
        Cp = (z ? vbf : kbf) + (long)m0 * 1024 + n0;
        ldc = 1024;
    } else {
        const int bb = b - 384;
        const int n0 = (bb & 31) * 128, m0 = (bb >> 5) * 128;
        Ap = hidb + (long)m0 * 2048;
        Bp = wq + (long)n0 * 2048;
        Cp = qbf + (long)m0 * 4096 + n0;
        ldc = 4096;
    }
    gemm128_f32b<__bf16>(Ap, Bp, Cp, 2048, 2048, 2048, ldc);
}

// ---------------------------------------------------------------------------
// Output projection, split-K=4 (512 blocks), fp32 partials.
// ---------------------------------------------------------------------------
__global__ __launch_bounds__(256) void gemm_wo_splitk(const __bf16* __restrict__ A,
                                                      const float* __restrict__ B,
                                                      float* __restrict__ po) {
    const int m0 = blockIdx.y * 128;
    const int n0 = blockIdx.x * 128;
    const int koff = blockIdx.z * 1024;
    float* C = po + (long)blockIdx.z * 1024 * 2048;
    gemm128_f32b<float>(A + (long)m0 * 4096 + koff, B + (long)n0 * 4096 + koff,
                        C + (long)m0 * 2048 + n0, 1024, 4096, 4096, 2048);
}

__global__ __launch_bounds__(256) void add4(const float* __restrict__ po,
                                            float* __restrict__ out, int n4) {
    int i = blockIdx.x * 256 + threadIdx.x;
    int stride = gridDim.x * 256;
    const long seg = (long)1024 * 2048 / 4;
    for (; i < n4; i += stride) {
        float4 a = ((const float4*)po)[i];
        float4 b = ((const float4*)po)[i + seg];
        float4 c = ((const float4*)po)[i + 2 * seg];
        float4 d = ((const float4*)po)[i + 3 * seg];
        float4 o;
        o.x = (a.x + b.x) + (c.x + d.x);
        o.y = (a.y + b.y) + (c.y + d.y);
        o.z = (a.z + b.z) + (c.z + d.z);
        o.w = (a.w + b.w) + (c.w + d.w);
        ((float4*)out)[i] = o;
    }
}

// ---------------------------------------------------------------------------
// Fused RMSNorm+RoPE for q (z=0) and k (z=1), in place.
// ---------------------------------------------------------------------------
__global__ __launch_bounds__(256) void rmsnorm_rope2(__bf16* __restrict__ xq,
                                                     const float* __restrict__ wq,
                                                     __bf16* __restrict__ xk,
                                                     const float* __restrict__ wk,
                                                     const float* __restrict__ cosb,
                                                     const float* __restrict__ sinb) {
    const int z = blockIdx.y;
    __bf16*      x = z ? xk : xq;
    const float* w = z ? wk : wq;
    const int nheads     = z ? 8 : 32;
    const int row_stride = z ? 1024 : 4096;
    const int pos_offset = z ? 0 : 2048;
    const float outscale = z ? 1.0f : 0.08838834764831845f;
    const int nitems     = z ? 3072 * 8 : 1024 * 32;

    int item = blockIdx.x * 4 + (threadIdx.x >> 6);
    int lane = threadIdx.x & 63;
    if (item >= nitems) return;
    int row = item / nheads;
    int head = item - row * nheads;
    __bf16* p = x + (long)row * row_stride + head * HD;

    float x1 = (float)p[lane], x2 = (float)p[lane + 64];
    float ss = x1 * x1 + x2 * x2;
#pragma unroll
    for (int o = 32; o >= 1; o >>= 1) ss += __shfl_xor(ss, o);
    float r = rsqrtf(ss * (1.0f / 128.0f) + 1e-6f) * outscale;

    int pos = pos_offset + row;
    float c1 = cosb[pos * HD + lane], c2 = cosb[pos * HD + lane + 64];
    float s1 = sinb[pos * HD + lane], s2 = sinb[pos * HD + lane + 64];
    float y1 = x1 * r * w[lane];
    float y2 = x2 * r * w[lane + 64];
    p[lane]      = (__bf16)(y1 * c1 - y2 * s1);
    p[lane + 64] = (__bf16)(y2 * c2 + y1 * s2);
}

// ---------------------------------------------------------------------------
// V transpose: vbf[t][g*128+d] -> vt[g][d][t]
// ---------------------------------------------------------------------------
__global__ __launch_bounds__(256) void transpose_v(const __bf16* __restrict__ v,
                                                   __bf16* __restrict__ vt) {
    __shared__ __bf16 T[64][68];
    const int tid = threadIdx.x;
    const int t0 = blockIdx.x * 64;
    const int d0 = blockIdx.y * 64;
    const int g  = blockIdx.z;
    const __bf16* src = v + (long)t0 * 1024 + g * 128 + d0;
#pragma unroll
    for (int i = 0; i < 4; i++) {
        int idx = tid + i * 256;
        int r = idx >> 4, c4 = (idx & 15) * 4;
        *(bf16x4*)&T[r][c4] = *(const bf16x4*)(src + (long)r * 1024 + c4);
    }
    __syncthreads();
    __bf16* dst = vt + (long)g * 128 * 3072 + (long)d0 * 3072 + t0;
#pragma unroll
    for (int i = 0; i < 4; i++) {
        int idx = tid + i * 256;
        int r = idx >> 4, c4 = (idx & 15) * 4;
        bf16x4 o;
        o[0] = T[c4 + 0][r]; o[1] = T[c4 + 1][r];
        o[2] = T[c4 + 2][r]; o[3] = T[c4 + 3][r];
        *(bf16x4*)(dst + (long)r * 3072 + c4) = o;
    }
}

// ---------------------------------------------------------------------------
// Split-K flash attention, 128 q-rows per block (4 waves x 2 m-tiles of 16).
// S computed TRANSPOSED (S^T = K Q^T, pure operand swap: A/B fragment lane
// layouts are identical for 16x16x32) so P exits with t in the register
// direction -> P->LDS is 8 packed ds_write_b64 per wave-tile instead of 32
// scalar b16 writes, and the row-sum is lane-local. PV phase, O layout,
// epilogue and merge are unchanged. Ps aliases Ks (stride 68).
// ---------------------------------------------------------------------------
__global__ __launch_bounds__(256) void flash_attn_splitk(const __bf16* __restrict__ qb,
                                                         const __bf16* __restrict__ kb,
                                                         const __bf16* __restrict__ vtg,
                                                         __bf16* __restrict__ Opart0,
                                                         __bf16* __restrict__ Opart1,
                                                         float* __restrict__ lsum) {
    __shared__ __bf16 KsU[64 * 136];   // Ks[t][d] stride 136; Ps aliased (4*32*68 = 8704)
    __shared__ __bf16 Vs[128][72];     // [d][t]
#define KS(r, c) KsU[(r) * 136 + (c)]
#define PS(w_, m_, t_) KsU[(w_) * 2176 + (m_) * 68 + (t_)]

    const int tid  = threadIdx.x;
    const int lane = tid & 63;
    const int w    = tid >> 6;
    const int n    = lane & 15;
    const int quad = lane >> 4;

    const int bid = blockIdx.x;        // 0..255
    const int s   = blockIdx.y;
    const int g  = bid & 7;
    const int jj = bid >> 3;           // 0..31
    const int h  = g * 4 + (jj & 3);
    const int qt = jj >> 2;            // 0..7, 128-row q tiles

    const int qr0 = qt * 128 + w * 16; // m-tile 0 base; m-tile 1 = +64

    bf16x8 qf[2][4];
#pragma unroll
    for (int mt = 0; mt < 2; mt++) {
        const __bf16* qp = qb + (long)(qr0 + mt * 64 + n) * 4096 + h * 128 + quad * 8;
        qf[mt][0] = *(const bf16x8*)(qp);
        qf[mt][1] = *(const bf16x8*)(qp + 32);
        qf[mt][2] = *(const bf16x8*)(qp + 64);
        qf[mt][3] = *(const bf16x8*)(qp + 96);
    }

    f32x4 O[2][8];
    const f32x4 fzero = {0.f, 0.f, 0.f, 0.f};
#pragma unroll
    for (int mt = 0; mt < 2; mt++)
#pragma unroll
        for (int dt = 0; dt < 8; dt++) O[mt][dt] = fzero;
    float l_loc[2] = {0.f, 0.f};       // lane-local: lane n16 owns q-row qr0+mt*64+n

    const int ntot = 34 + 2 * qt;      // even
    const int half = ntot >> 1;
    const int tbeg = s ? half : 0;
    const int tend = s ? ntot : half;

    const int krr = tid >> 4, kc8 = (tid & 15) * 8;
    const int vrr = tid >> 3, vc8 = (tid & 7) * 8;
    const __bf16* kp = kb + g * 128 + (long)(tbeg * 64 + krr) * 1024 + kc8;
    const __bf16* vp = vtg + (long)g * 128 * 3072 + (long)vrr * 3072 + tbeg * 64 + vc8;

    for (int tt = tbeg; tt < tend; tt++) {
#pragma unroll
        for (int i = 0; i < 4; i++)
            *(bf16x8*)&KS(krr + i * 16, kc8) = *(const bf16x8*)(kp + (long)i * 16 * 1024);
#pragma unroll
        for (int i = 0; i < 4; i++)
            *(bf16x8*)&Vs[vrr + i * 32][vc8] = *(const bf16x8*)(vp + (long)i * 32 * 3072);
        kp += 64 * 1024;
        vp += 64;
        __syncthreads();

        // S^T = K Q^T: A = K-frag, B = Q-frag (identical lane layouts).
        // Result: col(lane&15) = q-row, row(quad*4+r) = key t.
        f32x4 S[2][4];
#pragma unroll
        for (int nt = 0; nt < 4; nt++) {
            f32x4 a0 = fzero, a1 = fzero;
#pragma unroll
            for (int ks = 0; ks < 4; ks++) {
                bf16x8 kf = *(const bf16x8*)&KS(nt * 16 + n, ks * 32 + quad * 8);
                a0 = MFMA16(kf, qf[0][ks], a0);
                a1 = MFMA16(kf, qf[1][ks], a1);
            }
            S[0][nt] = a0;
            S[1][nt] = a1;
        }

        if (tt >= ntot - 2) {   // diagonal band spans the last two tiles
            const int t0 = tt * 64;
#pragma unroll
            for (int mt = 0; mt < 2; mt++) {
                const int lim = 2048 + qr0 + mt * 64 + n;   // q-row = lane index
#pragma unroll
                for (int nt = 0; nt < 4; nt++)
#pragma unroll
                    for (int r = 0; r < 4; r++) {
                        int t = t0 + nt * 16 + quad * 4 + r;
                        if (t > lim) S[mt][nt][r] = -1e30f;
                    }
            }
        }

        __syncthreads();   // all Ks reads done; Ps may overwrite

        // fixed-shift softmax; row-sum is lane-local (lane owns its q-row)
#pragma unroll
        for (int mt = 0; mt < 2; mt++)
#pragma unroll
            for (int nt = 0; nt < 4; nt++)
#pragma unroll
                for (int r = 0; r < 4; r++) {
                    float p = __expf(S[mt][nt][r] - MSTATIC);
                    S[mt][nt][r] = p;
                    l_loc[mt] += p;
                }

        // P -> LDS: packed b64 writes (4 consecutive t per (mt,nt))
#pragma unroll
        for (int mt = 0; mt < 2; mt++)
#pragma unroll
            for (int nt = 0; nt < 4; nt++) {
                bf16x4 pk;
#pragma unroll
                for (int r = 0; r < 4; r++) pk[r] = (__bf16)S[mt][nt][r];
                *(bf16x4*)&PS(w, mt * 16 + n, nt * 16 + quad * 4) = pk;
            }

        bf16x8 pa[2][2];
#pragma unroll
        for (int mt = 0; mt < 2; mt++)
#pragma unroll
            for (int kg = 0; kg < 2; kg++)
                pa[mt][kg] = *(const bf16x8*)&PS(w, mt * 16 + n, kg * 32 + quad * 8);

#pragma unroll
        for (int dt = 0; dt < 8; dt++) {
            bf16x8 vf0 = *(const bf16x8*)&Vs[dt * 16 + n][quad * 8];
            bf16x8 vf1 = *(const bf16x8*)&Vs[dt * 16 + n][32 + quad * 8];
#pragma unroll
            for (int mt = 0; mt < 2; mt++) {
                f32x4 acc = O[mt][dt];
                acc = MFMA16(pa[mt][0], vf0, acc);
                acc = MFMA16(pa[mt][1], vf1, acc);
                O[mt][dt] = acc;
            }
        }
        __syncthreads();
    }

    // row-sum: reduce across the 4 quads (lane already holds its row's partial)
#pragma unroll
    for (int mt = 0; mt < 2; mt++) {
        float sm = l_loc[mt];
        sm += __shfl_xor(sm, 16);
        sm += __shfl_xor(sm, 32);
        l_loc[mt] = sm;
    }

    __bf16* Op = s ? Opart1 : Opart0;
    const long tb = (long)(h * 8 + qt) * 128 * 128;
#pragma unroll
    for (int mt = 0; mt < 2; mt++)
#pragma unroll
        for (int dt = 0; dt < 8; dt++)
#pragma unroll
            for (int r = 0; r < 4; r++)
                Op[tb + (long)(mt * 64 + w * 16 + quad * 4 + r) * 128 + dt * 16 + n] =
                    (__bf16)O[mt][dt][r];
    if (quad == 0) {
        const int lb = (s * 256 + h * 8 + qt) * 128 + w * 16;
#pragma unroll
        for (int mt = 0; mt < 2; mt++)
            lsum[lb + mt * 64 + n] = l_loc[mt];
    }
#undef KS
#undef PS
}

// ---------------------------------------------------------------------------
// Additive merge of split-K partials -> normalized bf16 O over qbf.
// ---------------------------------------------------------------------------
__global__ __launch_bounds__(256) void flash_merge(const __bf16* __restrict__ O0,
                                                   const __bf16* __restrict__ O1,
                                                   const float* __restrict__ lsum,
                                                   __bf16* __restrict__ ob) {
    const int bx = blockIdx.x;         // 512: (h, qt, half64)
    const int h   = bx >> 4;
    const int r6  = bx & 15;
    const int qt  = r6 >> 1;
    const int sub = r6 & 1;
    const int row  = threadIdx.x >> 2;
    const int cseg = (threadIdx.x & 3) * 32;
    const int mrow = sub * 64 + row;

    const int tilei = h * 8 + qt;
    float inv = 1.0f / (lsum[tilei * 128 + mrow] + lsum[(256 + tilei) * 128 + mrow]);

    const long src = (long)tilei * 128 * 128 + (long)mrow * 128 + cseg;
    __bf16* dst = ob + (long)(qt * 128 + mrow) * 4096 + h * 128 + cseg;
#pragma unroll
    for (int j = 0; j < 4; j++) {
        bf16x8 x0 = *(const bf16x8*)(O0 + src + j * 8);
        bf16x8 x1 = *(const bf16x8*)(O1 + src + j * 8);
        bf16x8 o;
#pragma unroll
        for (int k = 0; k < 8; k++)
            o[k] = (__bf16)(((float)x0[k] + (float)x1[k]) * inv);
        *(bf16x8*)(dst + j * 8) = o;
    }
}

// ---------------------------------------------------------------------------
extern "C" void kernel_launch(void* const* d_in, const int* in_sizes, int n_in,
                              void* d_out, int out_size, void* d_ws, size_t ws_size,
                              hipStream_t stream) {
    const float* hidden = (const float*)d_in[0];
    const float* target = (const float*)d_in[1];
    const float* cosb   = (const float*)d_in[2];
    const float* sinb   = (const float*)d_in[3];
    const float* wq = (const float*)d_in[5];
    const float* wk = (const float*)d_in[6];
    const float* wv = (const float*)d_in[7];
    const float* wo = (const float*)d_in[8];
    const float* qw = (const float*)d_in[9];
    const float* kw = (const float*)d_in[10];
    float* out = (float*)d_out;

    // 40 MB workspace, phased overlays (launch order guarantees safety):
    char* ws = (char*)d_ws;
    const long MB = 1 << 20;
    __bf16* qbf  = (__bf16*)(ws);             // @0..8    q / attn out (live throughout)
    __bf16* kbf  = (__bf16*)(ws + 8 * MB);    // @8..14   k (dead after flash)
    __bf16* vbf  = (__bf16*)(ws + 14 * MB);   // @14..20  v (dead after transpose)
    __bf16* hidb = (__bf16*)(ws + 20 * MB);   // @20..24  (dead after gemm_kvq)
    __bf16* tgtb = (__bf16*)(ws + 24 * MB);   // @24..32  (dead after gemm_kvq)
    __bf16* vtg  = (__bf16*)(ws + 24 * MB);   // @24..30  (post-kvq)
    __bf16* Op1  = (__bf16*)(ws + 14 * MB);   // @14..22  (post-transpose)
    float*  lbuf = (float*)(ws + 22 * MB);    // @22..22.25
    __bf16* Op0  = (__bf16*)(ws + 30 * MB);   // @30..38
    float*  po   = (float*)(ws + 8 * MB);     // @8..40   wo partials (post-merge)

    dim3 blk(256);

    // activations -> bf16
    conv2_f32_bf16<<<dim3(1024, 2), blk, 0, stream>>>(
        target, tgtb, (2048 * 2048) / 4, hidden, hidb, (1024 * 2048) / 4);

    // all three projections, one launch (weights fp32, converted in-GEMM)
    gemm_kvq<<<640, blk, 0, stream>>>(tgtb, hidb, wk, wv, wq, kbf, vbf, qbf);

    // fused RMSNorm + RoPE (q and k)
    rmsnorm_rope2<<<dim3(8192, 2), blk, 0, stream>>>(qbf, qw, kbf, kw, cosb, sinb);

    // V transpose -> [g][d][t]
    transpose_v<<<dim3(48, 2, 8), blk, 0, stream>>>(vbf, vtg);

    // split-K flash attention (512 blocks, 128 q-rows each) + additive merge
    flash_attn_splitk<<<dim3(256, 2), blk, 0, stream>>>(qbf, kbf, vtg, Op0, Op1, lbuf);
    flash_merge<<<512, blk, 0, stream>>>(Op0, Op1, lbuf, qbf);

    // output projection: split-K=4 (512 blocks) + reduce
    gemm_wo_splitk<<<dim3(16, 8, 4), blk, 0, stream>>>(qbf, wo, po);
    add4<<<1024, blk, 0, stream>>>(po, out, (1024 * 2048) / 4);
}